// Round 7
// baseline (124.758 us; speedup 1.0000x reference)
//
#include <hip/hip_runtime.h>
#include <math.h>

#define NN   20000
#define NE   320000
#define FIN  128
#define FHID 256
#define FOUT 64
#define CLDS 268   // fp32 C-tile LDS row stride

typedef __attribute__((ext_vector_type(8))) __bf16 bf16x8;
typedef __attribute__((ext_vector_type(4))) float  f32x4;

union FragU { unsigned short us[8]; bf16x8 v; uint4 q; };

static __device__ __forceinline__ unsigned short f2bf(float f) {
    unsigned u = __float_as_uint(f);
    return (unsigned short)((u + 0x7FFFu + ((u >> 16) & 1u)) >> 16);
}

// ---------- CSR build ----------
__global__ void k_init(float* deg, int* cnt) {
    int i = blockIdx.x * blockDim.x + threadIdx.x;
    if (i < NN) { deg[i] = 1.0f; cnt[i] = 0; }   // self-loop weight 1.0 pre-added
}

__global__ void k_deg(const int* __restrict__ dst, const float* __restrict__ ew,
                      float* __restrict__ deg, int* __restrict__ cnt) {
    int e = blockIdx.x * blockDim.x + threadIdx.x;
    if (e < NE) {
        int d = dst[e];
        atomicAdd(&deg[d], ew[e]);
        atomicAdd(&cnt[d], 1);
    }
}

// multi-block scan, stage 1: per-block inclusive scan of cnt; also computes dinv
__global__ __launch_bounds__(1024) void k_scan1(
    const int* __restrict__ cnt, const float* __restrict__ deg,
    float* __restrict__ dinv, int* __restrict__ off, int* __restrict__ bsum) {
    __shared__ int wsum[16];
    int tid = threadIdx.x, lane = tid & 63, w = tid >> 6;
    int i = blockIdx.x * 1024 + tid;
    int v = (i < NN) ? cnt[i] : 0;
    if (i < NN) {
        float dg = deg[i];
        dinv[i] = dg > 0.0f ? rsqrtf(dg) : 0.0f;
    }
    int sc = v;
    #pragma unroll
    for (int d = 1; d < 64; d <<= 1) {
        int t = __shfl_up(sc, d, 64);
        if (lane >= d) sc += t;
    }
    if (lane == 63) wsum[w] = sc;
    __syncthreads();
    if (w == 0) {
        int ws_ = (lane < 16) ? wsum[lane] : 0;
        #pragma unroll
        for (int d = 1; d < 16; d <<= 1) {
            int t = __shfl_up(ws_, d, 64);
            if (lane >= d) ws_ += t;
        }
        if (lane < 16) wsum[lane] = ws_;
    }
    __syncthreads();
    int inc = sc + (w ? wsum[w - 1] : 0);
    if (i < NN) off[i + 1] = inc;
    if (tid == 1023) bsum[blockIdx.x] = inc;
}

// stage 2: exclusive scan of the 20 block sums (single wave)
__global__ void k_scan2(int* bsum) {
    int l = threadIdx.x;
    int v = (l < 20) ? bsum[l] : 0;
    int sc = v;
    #pragma unroll
    for (int d = 1; d < 32; d <<= 1) {
        int t = __shfl_up(sc, d, 64);
        if (l >= d) sc += t;
    }
    if (l < 20) bsum[l] = sc - v;
}

// stage 3: add block prefix; zero cnt for scatter
__global__ __launch_bounds__(1024) void k_scan3(int* __restrict__ off,
                                                const int* __restrict__ bsum,
                                                int* __restrict__ cnt) {
    int i = blockIdx.x * 1024 + threadIdx.x;
    if (i < NN) { off[i + 1] += bsum[blockIdx.x]; cnt[i] = 0; }
    if (i == 0) off[0] = 0;
}

// scatter with fully-precomputed coefficient: coef = ew * dinv[s] * dinv[d]
__global__ void k_scatter(const int* __restrict__ src, const int* __restrict__ dst,
                          const float* __restrict__ ew, const float* __restrict__ dinv,
                          const int* __restrict__ off, int* __restrict__ cnt,
                          int2* __restrict__ ep) {
    int e = blockIdx.x * blockDim.x + threadIdx.x;
    if (e < NE) {
        int d = dst[e], s = src[e];
        float c = ew[e] * dinv[s] * dinv[d];
        int p = off[d] + atomicAdd(&cnt[d], 1);
        ep[p] = make_int2(s, __float_as_int(c));
    }
}

// ---------- pack W ([K][N] fp32, row-major) into MFMA B-fragment tiles, hi/lo bf16 ----------
__global__ void k_wpack(const float* __restrict__ W, int K, int N,
                        unsigned short* __restrict__ hi, unsigned short* __restrict__ lo) {
    int t = blockIdx.x * blockDim.x + threadIdx.x;
    int NT = N >> 4, KT = K >> 5;
    if (t >= KT * NT * 64) return;
    int lane = t & 63;
    int tile = t >> 6;
    int nt = tile % NT, kt = tile / NT;
    int col = nt * 16 + (lane & 15);
    int k0 = kt * 32 + (lane >> 4) * 8;
    #pragma unroll
    for (int j = 0; j < 8; ++j) {
        float w = W[(size_t)(k0 + j) * N + col];
        unsigned short h = f2bf(w);
        unsigned short l = f2bf(w - __uint_as_float((unsigned)h << 16));
        hi[(size_t)t * 8 + j] = h;
        lo[(size_t)t * 8 + j] = l;
    }
}

// ---------- layer-1 aggregate: A = S @ X ----------
// wave per node; half-wave (32 lanes x float4 = full 512B row) per EDGE.
// Edges split: half h takes p+4h+j (unroll 4) -> 8 gathers in flight, chain deg/8.
__global__ __launch_bounds__(256) void k_aggx(
    const float* __restrict__ x, const int2* __restrict__ ep,
    const float* __restrict__ dinv, const int* __restrict__ off,
    float* __restrict__ A) {
    int w = threadIdx.x >> 6, lane = threadIdx.x & 63;
    int h = lane >> 5, l = lane & 31;
    int n = (blockIdx.x << 2) + w;
    const float* xc = x + (l << 2);
    float ax = 0.f, ay = 0.f, az = 0.f, aw = 0.f;
    int p = off[n], p1 = off[n + 1];
    for (; p + 8 <= p1; p += 8) {
        int b = p + (h << 2);
        int2 e0 = ep[b], e1 = ep[b + 1], e2 = ep[b + 2], e3 = ep[b + 3];
        float4 v0 = *(const float4*)(xc + ((size_t)e0.x << 7));
        float4 v1 = *(const float4*)(xc + ((size_t)e1.x << 7));
        float4 v2 = *(const float4*)(xc + ((size_t)e2.x << 7));
        float4 v3 = *(const float4*)(xc + ((size_t)e3.x << 7));
        float c0 = __int_as_float(e0.y), c1 = __int_as_float(e1.y);
        float c2 = __int_as_float(e2.y), c3 = __int_as_float(e3.y);
        ax += c0 * v0.x + c1 * v1.x + c2 * v2.x + c3 * v3.x;
        ay += c0 * v0.y + c1 * v1.y + c2 * v2.y + c3 * v3.y;
        az += c0 * v0.z + c1 * v1.z + c2 * v2.z + c3 * v3.z;
        aw += c0 * v0.w + c1 * v1.w + c2 * v2.w + c3 * v3.w;
    }
    for (; p < p1; p += 2) {
        int idx = p + h;
        if (idx < p1) {
            int2 e = ep[idx];
            float4 v = *(const float4*)(xc + ((size_t)e.x << 7));
            float c = __int_as_float(e.y);
            ax += c * v.x; ay += c * v.y; az += c * v.z; aw += c * v.w;
        }
    }
    // merge the two halves (lane i <-> i^32)
    ax += __shfl_xor(ax, 32, 64);
    ay += __shfl_xor(ay, 32, 64);
    az += __shfl_xor(az, 32, 64);
    aw += __shfl_xor(aw, 32, 64);
    float dn = dinv[n];
    float s2 = dn * dn;
    float4 xv = *(const float4*)(xc + ((size_t)n << 7));
    if (h == 0) {
        ax += s2 * xv.x; ay += s2 * xv.y; az += s2 * xv.z; aw += s2 * xv.w;
        *(float4*)(A + ((size_t)n << 7) + (l << 2)) = make_float4(ax, ay, az, aw);
    }
}

// ---------- fused MLP on matrix cores, split-bf16 (unchanged from round 6) ----------
__global__ __launch_bounds__(256, 4) void k_mlp(
    const float* __restrict__ A,
    const unsigned short* __restrict__ W1h, const unsigned short* __restrict__ W1l,
    const float* __restrict__ b1,
    const unsigned short* __restrict__ W2h, const unsigned short* __restrict__ W2l,
    float* __restrict__ G) {
    __shared__ unsigned short ApkH[4 * 64 * 8];
    __shared__ unsigned short ApkL[4 * 64 * 8];
    __shared__ float ldsC[16 * CLDS];
    int tid = threadIdx.x;
    int lane = tid & 63, w = tid >> 6;
    int row0 = blockIdx.x * 16;
    int colb = lane & 15, kg = lane >> 4;
    int rowb = kg * 4;

    {
        const float* ap = A + (size_t)(row0 + colb) * FIN + w * 32 + kg * 8;
        float4 f0 = *(const float4*)ap;
        float4 f1 = *(const float4*)(ap + 4);
        float fs[8] = {f0.x, f0.y, f0.z, f0.w, f1.x, f1.y, f1.z, f1.w};
        FragU h, l;
        #pragma unroll
        for (int j = 0; j < 8; ++j) {
            h.us[j] = f2bf(fs[j]);
            l.us[j] = f2bf(fs[j] - __uint_as_float((unsigned)h.us[j] << 16));
        }
        *(uint4*)&ApkH[tid * 8] = h.q;
        *(uint4*)&ApkL[tid * 8] = l.q;
    }
    __syncthreads();

    {
        f32x4 acc[4];
        #pragma unroll
        for (int f = 0; f < 4; ++f) acc[f] = (f32x4){0.f, 0.f, 0.f, 0.f};
        #pragma unroll
        for (int kt = 0; kt < 4; ++kt) {
            bf16x8 ah = *(const bf16x8*)&ApkH[(kt * 64 + lane) * 8];
            bf16x8 al = *(const bf16x8*)&ApkL[(kt * 64 + lane) * 8];
            #pragma unroll
            for (int f = 0; f < 4; ++f) {
                int nt = w * 4 + f;
                size_t o8 = ((size_t)(kt * 16 + nt) * 64 + lane) * 8;
                bf16x8 bh = *(const bf16x8*)&W1h[o8];
                bf16x8 bl = *(const bf16x8*)&W1l[o8];
                acc[f] = __builtin_amdgcn_mfma_f32_16x16x32_bf16(ah, bh, acc[f], 0, 0, 0);
                acc[f] = __builtin_amdgcn_mfma_f32_16x16x32_bf16(ah, bl, acc[f], 0, 0, 0);
                acc[f] = __builtin_amdgcn_mfma_f32_16x16x32_bf16(al, bh, acc[f], 0, 0, 0);
                acc[f] = __builtin_amdgcn_mfma_f32_16x16x32_bf16(al, bl, acc[f], 0, 0, 0);
            }
        }
        #pragma unroll
        for (int f = 0; f < 4; ++f) {
            int nt = w * 4 + f;
            float bias = b1[nt * 16 + colb];
            #pragma unroll
            for (int r = 0; r < 4; ++r)
                ldsC[(rowb + r) * CLDS + nt * 16 + colb] = fmaxf(acc[f][r] + bias, 0.f);
        }
    }
    __syncthreads();

    {
        f32x4 acc2 = (f32x4){0.f, 0.f, 0.f, 0.f};
        #pragma unroll
        for (int kt = 0; kt < 8; ++kt) {
            const float* cp = &ldsC[colb * CLDS + kt * 32 + kg * 8];
            float4 c0 = *(const float4*)cp;
            float4 c1 = *(const float4*)(cp + 4);
            float fs[8] = {c0.x, c0.y, c0.z, c0.w, c1.x, c1.y, c1.z, c1.w};
            FragU h, l;
            #pragma unroll
            for (int j = 0; j < 8; ++j) {
                h.us[j] = f2bf(fs[j]);
                l.us[j] = f2bf(fs[j] - __uint_as_float((unsigned)h.us[j] << 16));
            }
            size_t o8 = ((size_t)(kt * 4 + w) * 64 + lane) * 8;
            bf16x8 bh = *(const bf16x8*)&W2h[o8];
            bf16x8 bl = *(const bf16x8*)&W2l[o8];
            acc2 = __builtin_amdgcn_mfma_f32_16x16x32_bf16(h.v, bh, acc2, 0, 0, 0);
            acc2 = __builtin_amdgcn_mfma_f32_16x16x32_bf16(h.v, bl, acc2, 0, 0, 0);
            acc2 = __builtin_amdgcn_mfma_f32_16x16x32_bf16(l.v, bh, acc2, 0, 0, 0);
            acc2 = __builtin_amdgcn_mfma_f32_16x16x32_bf16(l.v, bl, acc2, 0, 0, 0);
        }
        #pragma unroll
        for (int r = 0; r < 4; ++r)
            G[(size_t)(row0 + rowb + r) * FOUT + w * 16 + colb] = acc2[r];
    }
}

// ---------- layer-2 aggregate + bias + softmax ----------
// wave per node; quarter-wave (16 lanes x float4 = full 256B row) per EDGE.
// Quarter q takes edges p+2q+j (unroll 2) -> 8 gathers in flight, chain deg/8.
__global__ __launch_bounds__(256) void k_agg2sm(
    const float* __restrict__ G, const int2* __restrict__ ep,
    const float* __restrict__ dinv, const int* __restrict__ off,
    const float* __restrict__ b2, float* __restrict__ out) {
    int w = threadIdx.x >> 6, lane = threadIdx.x & 63;
    int q = lane >> 4, l = lane & 15;
    int n = (blockIdx.x << 2) + w;
    const float* gc = G + (l << 2);
    float ax = 0.f, ay = 0.f, az = 0.f, aw = 0.f;
    int p = off[n], p1 = off[n + 1];
    for (; p + 8 <= p1; p += 8) {
        int b = p + (q << 1);
        int2 e0 = ep[b], e1 = ep[b + 1];
        float4 v0 = *(const float4*)(gc + ((size_t)e0.x << 6));
        float4 v1 = *(const float4*)(gc + ((size_t)e1.x << 6));
        float c0 = __int_as_float(e0.y), c1 = __int_as_float(e1.y);
        ax += c0 * v0.x + c1 * v1.x;
        ay += c0 * v0.y + c1 * v1.y;
        az += c0 * v0.z + c1 * v1.z;
        aw += c0 * v0.w + c1 * v1.w;
    }
    for (; p < p1; p += 4) {
        int idx = p + q;
        if (idx < p1) {
            int2 e = ep[idx];
            float4 v = *(const float4*)(gc + ((size_t)e.x << 6));
            float c = __int_as_float(e.y);
            ax += c * v.x; ay += c * v.y; az += c * v.z; aw += c * v.w;
        }
    }
    // merge quarters (xor 16, then 32)
    ax += __shfl_xor(ax, 16, 64); ay += __shfl_xor(ay, 16, 64);
    az += __shfl_xor(az, 16, 64); aw += __shfl_xor(aw, 16, 64);
    ax += __shfl_xor(ax, 32, 64); ay += __shfl_xor(ay, 32, 64);
    az += __shfl_xor(az, 32, 64); aw += __shfl_xor(aw, 32, 64);

    float dn = dinv[n];
    float s2 = dn * dn;
    float4 gv = *(const float4*)(gc + ((size_t)n << 6));
    float4 bv = *(const float4*)&b2[l << 2];
    ax += s2 * gv.x + bv.x; ay += s2 * gv.y + bv.y;
    az += s2 * gv.z + bv.z; aw += s2 * gv.w + bv.w;

    float m = fmaxf(fmaxf(ax, ay), fmaxf(az, aw));
    #pragma unroll
    for (int d = 8; d; d >>= 1) m = fmaxf(m, __shfl_xor(m, d, 16));
    float ex = __expf(ax - m), ey = __expf(ay - m), ez = __expf(az - m), ew_ = __expf(aw - m);
    float s = ex + ey + ez + ew_;
    #pragma unroll
    for (int d = 8; d; d >>= 1) s += __shfl_xor(s, d, 16);
    if (q == 0) {
        float inv = 1.0f / s;
        *(float4*)&out[((size_t)n << 6) + (l << 2)] =
            make_float4(ex * inv, ey * inv, ez * inv, ew_ * inv);
    }
}

extern "C" void kernel_launch(void* const* d_in, const int* in_sizes, int n_in,
                              void* d_out, int out_size, void* d_ws, size_t ws_size,
                              hipStream_t stream) {
    const float* x  = (const float*)d_in[0];
    const int*   ei = (const int*)d_in[1];     // [2, NE]
    const float* ew = (const float*)d_in[2];
    // d_in[3..6] = W_gat, att_src, att_dst, b_gat — DEAD in the reference.
    const float* W1 = (const float*)d_in[7];
    const float* b1 = (const float*)d_in[8];
    const float* W2 = (const float*)d_in[9];
    const float* b2 = (const float*)d_in[10];

    const int* srcv = ei;
    const int* dstv = ei + NE;

    char* ws = (char*)d_ws;
    size_t o = 0;
    auto alloc = [&](size_t bytes) {
        void* p = ws + o;
        o = (o + bytes + 255) & ~(size_t)255;
        return p;
    };
    float* deg  = (float*)alloc(NN * sizeof(float));
    float* dinv = (float*)alloc(NN * sizeof(float));
    int*   cnt  = (int*)alloc(NN * sizeof(int));
    int*   off  = (int*)alloc((NN + 1) * sizeof(int));
    int*   bsum = (int*)alloc(32 * sizeof(int));
    int2*  ep   = (int2*)alloc((size_t)NE * sizeof(int2));
    float* A    = (float*)alloc((size_t)NN * FIN * sizeof(float));
    float* G    = (float*)alloc((size_t)NN * FOUT * sizeof(float));
    unsigned short* W1h = (unsigned short*)alloc(FIN * FHID * sizeof(unsigned short));
    unsigned short* W1l = (unsigned short*)alloc(FIN * FHID * sizeof(unsigned short));
    unsigned short* W2h = (unsigned short*)alloc(FHID * FOUT * sizeof(unsigned short));
    unsigned short* W2l = (unsigned short*)alloc(FHID * FOUT * sizeof(unsigned short));

    k_init   <<<(NN + 255) / 256, 256, 0, stream>>>(deg, cnt);
    k_deg    <<<(NE + 255) / 256, 256, 0, stream>>>(dstv, ew, deg, cnt);
    k_wpack  <<<16, 256, 0, stream>>>(W1, FIN, FHID, W1h, W1l);
    k_wpack  <<<8,  256, 0, stream>>>(W2, FHID, FOUT, W2h, W2l);
    k_scan1  <<<20, 1024, 0, stream>>>(cnt, deg, dinv, off, bsum);
    k_scan2  <<<1, 64, 0, stream>>>(bsum);
    k_scan3  <<<20, 1024, 0, stream>>>(off, bsum, cnt);
    k_scatter<<<(NE + 255) / 256, 256, 0, stream>>>(srcv, dstv, ew, dinv, off, cnt, ep);
    k_aggx   <<<NN / 4, 256, 0, stream>>>(x, ep, dinv, off, A);
    k_mlp    <<<NN / 16, 256, 0, stream>>>(A, W1h, W1l, b1, W2h, W2l, G);
    k_agg2sm <<<NN / 4, 256, 0, stream>>>(G, ep, dinv, off, b2, (float*)d_out);
}

// Round 8
// 98.972 us; speedup vs baseline: 1.2605x; 1.2605x over previous
//
#include <hip/hip_runtime.h>
#include <math.h>

#define NN   20000
#define NE   320000
#define FIN  128
#define FHID 256
#define FOUT 64
#define CLDS 268   // fp32 C-tile LDS row stride
#define ALDS 132   // fp32 A-tile LDS row stride (132%32=4 -> 2-way max on frag reads)

typedef __attribute__((ext_vector_type(8))) __bf16 bf16x8;
typedef __attribute__((ext_vector_type(4))) float  f32x4;

union FragU { unsigned short us[8]; bf16x8 v; uint4 q; };

static __device__ __forceinline__ unsigned short f2bf(float f) {
    unsigned u = __float_as_uint(f);
    return (unsigned short)((u + 0x7FFFu + ((u >> 16) & 1u)) >> 16);
}

// ---------- W-pack device body: W [K][N] fp32 -> MFMA B-fragment tiles, hi/lo bf16 ----------
static __device__ __forceinline__ void wpack_body(
    const float* __restrict__ W, int K, int N,
    unsigned short* __restrict__ hi, unsigned short* __restrict__ lo, int t) {
    int NT = N >> 4, KT = K >> 5;
    if (t >= KT * NT * 64) return;
    int lane = t & 63;
    int tile = t >> 6;
    int nt = tile % NT, kt = tile / NT;
    int col = nt * 16 + (lane & 15);
    int k0 = kt * 32 + (lane >> 4) * 8;
    #pragma unroll
    for (int j = 0; j < 8; ++j) {
        float w = W[(size_t)(k0 + j) * N + col];
        unsigned short h = f2bf(w);
        unsigned short l = f2bf(w - __uint_as_float((unsigned)h << 16));
        hi[(size_t)t * 8 + j] = h;
        lo[(size_t)t * 8 + j] = l;
    }
}

// ---------- prep: init packed deg/cnt + pack W1 + pack W2 (blockIdx-partitioned) ----------
// P[i] layout: bits[63:40] = edge count, bits[39:0] = deg * 2^32 (fixed point).
// Init = self-loop weight 1.0 -> 1<<32.
__global__ void k_prep(unsigned long long* __restrict__ P,
                       const float* __restrict__ W1, unsigned short* __restrict__ W1h,
                       unsigned short* __restrict__ W1l,
                       const float* __restrict__ W2, unsigned short* __restrict__ W2h,
                       unsigned short* __restrict__ W2l) {
    int b = blockIdx.x, tid = threadIdx.x;
    if (b < 79) {
        int i = b * 256 + tid;
        if (i < NN) P[i] = (1ULL << 32);
    } else if (b < 95) {
        wpack_body(W1, FIN, FHID, W1h, W1l, (b - 79) * 256 + tid);
    } else {
        wpack_body(W2, FHID, FOUT, W2h, W2l, (b - 95) * 256 + tid);
    }
}

// ---------- degree + count in ONE u64 atomic per edge ----------
__global__ void k_deg(const int* __restrict__ dst, const float* __restrict__ ew,
                      unsigned long long* __restrict__ P) {
    int e = blockIdx.x * blockDim.x + threadIdx.x;
    if (e < NE) {
        int d = dst[e];
        // ew in [0,1): ew*2^32 exact in fp32 (pow2 scale), fits low 40 bits
        unsigned long long add = (1ULL << 40) + (unsigned long long)(ew[e] * 4294967296.0f);
        atomicAdd(&P[d], add);
    }
}

// scan stage 1: per-block inclusive scan of counts; also dinv from packed deg
__global__ __launch_bounds__(1024) void k_scan1(
    const unsigned long long* __restrict__ P,
    float* __restrict__ dinv, int* __restrict__ off, int* __restrict__ bsum) {
    __shared__ int wsum[16];
    int tid = threadIdx.x, lane = tid & 63, w = tid >> 6;
    int i = blockIdx.x * 1024 + tid;
    unsigned long long pv = (i < NN) ? P[i] : 0ULL;
    int v = (int)(pv >> 40);
    if (i < NN) {
        float dg = (float)(pv & 0xFFFFFFFFFFULL) * 0x1p-32f;
        dinv[i] = dg > 0.0f ? rsqrtf(dg) : 0.0f;
    }
    int sc = v;
    #pragma unroll
    for (int d = 1; d < 64; d <<= 1) {
        int t = __shfl_up(sc, d, 64);
        if (lane >= d) sc += t;
    }
    if (lane == 63) wsum[w] = sc;
    __syncthreads();
    if (w == 0) {
        int ws_ = (lane < 16) ? wsum[lane] : 0;
        #pragma unroll
        for (int d = 1; d < 16; d <<= 1) {
            int t = __shfl_up(ws_, d, 64);
            if (lane >= d) ws_ += t;
        }
        if (lane < 16) wsum[lane] = ws_;
    }
    __syncthreads();
    int inc = sc + (w ? wsum[w - 1] : 0);
    if (i < NN) off[i + 1] = inc;
    if (tid == 1023) bsum[blockIdx.x] = inc;
}

// scan stage 2+3 fused: each block inlines the 20-element block-sum scan, adds prefix, zeroes cnt
__global__ __launch_bounds__(1024) void k_scan3(int* __restrict__ off,
                                                const int* __restrict__ bsum,
                                                int* __restrict__ cnt) {
    __shared__ int sp;
    int tid = threadIdx.x;
    if (tid < 32) {
        int v = (tid < 20) ? bsum[tid] : 0;
        int sc = v;
        #pragma unroll
        for (int d = 1; d < 32; d <<= 1) {
            int t = __shfl_up(sc, d, 32);
            if (tid >= d) sc += t;
        }
        if (tid == (int)blockIdx.x) sp = sc - v;   // exclusive prefix for this block
    }
    __syncthreads();
    int i = blockIdx.x * 1024 + tid;
    if (i < NN) { off[i + 1] += sp; cnt[i] = 0; }
    if (i == 0) off[0] = 0;
}

// scatter with fully-precomputed coefficient: coef = ew * dinv[s] * dinv[d]
__global__ void k_scatter(const int* __restrict__ src, const int* __restrict__ dst,
                          const float* __restrict__ ew, const float* __restrict__ dinv,
                          const int* __restrict__ off, int* __restrict__ cnt,
                          int2* __restrict__ ep) {
    int e = blockIdx.x * blockDim.x + threadIdx.x;
    if (e < NE) {
        int d = dst[e], s = src[e];
        float c = ew[e] * dinv[s] * dinv[d];
        int p = off[d] + atomicAdd(&cnt[d], 1);
        ep[p] = make_int2(s, __float_as_int(c));
    }
}

// ---------- FUSED: A-rows aggregate (16 nodes) -> split-bf16 MFMA MLP -> G ----------
// Phase 0: 8 half-waves x 2 nodes each; 32 lanes x float4 = full 512B x-row per edge.
// Then: A-fragment staging from LDS, phase1 MFMA (W1), relu+bias, phase2 MFMA (W2).
__global__ __launch_bounds__(256, 4) void k_aggmlp(
    const float* __restrict__ x, const int2* __restrict__ ep,
    const float* __restrict__ dinv, const int* __restrict__ off,
    const unsigned short* __restrict__ W1h, const unsigned short* __restrict__ W1l,
    const float* __restrict__ b1,
    const unsigned short* __restrict__ W2h, const unsigned short* __restrict__ W2l,
    float* __restrict__ G) {
    __shared__ float ldsA[16 * ALDS];             // 8.25 KB
    __shared__ unsigned short ApkH[4 * 64 * 8];   // 4 KB
    __shared__ unsigned short ApkL[4 * 64 * 8];   // 4 KB
    __shared__ float ldsC[16 * CLDS];             // 17.2 KB
    int tid = threadIdx.x;
    int row0 = blockIdx.x * 16;

    // ---- phase 0: aggregate 16 node rows into ldsA ----
    {
        int hw = tid >> 5, l = tid & 31;
        const float* xc = x + (l << 2);
        #pragma unroll
        for (int rep = 0; rep < 2; ++rep) {
            int nl = hw + rep * 8;
            int n = row0 + nl;
            float ax = 0.f, ay = 0.f, az = 0.f, aw = 0.f;
            int p = off[n], p1 = off[n + 1];
            for (; p + 4 <= p1; p += 4) {
                int2 e0 = ep[p], e1 = ep[p + 1], e2 = ep[p + 2], e3 = ep[p + 3];
                float4 v0 = *(const float4*)(xc + ((size_t)e0.x << 7));
                float4 v1 = *(const float4*)(xc + ((size_t)e1.x << 7));
                float4 v2 = *(const float4*)(xc + ((size_t)e2.x << 7));
                float4 v3 = *(const float4*)(xc + ((size_t)e3.x << 7));
                float c0 = __int_as_float(e0.y), c1 = __int_as_float(e1.y);
                float c2 = __int_as_float(e2.y), c3 = __int_as_float(e3.y);
                ax += c0 * v0.x + c1 * v1.x + c2 * v2.x + c3 * v3.x;
                ay += c0 * v0.y + c1 * v1.y + c2 * v2.y + c3 * v3.y;
                az += c0 * v0.z + c1 * v1.z + c2 * v2.z + c3 * v3.z;
                aw += c0 * v0.w + c1 * v1.w + c2 * v2.w + c3 * v3.w;
            }
            for (; p < p1; ++p) {
                int2 e = ep[p];
                float4 v = *(const float4*)(xc + ((size_t)e.x << 7));
                float c = __int_as_float(e.y);
                ax += c * v.x; ay += c * v.y; az += c * v.z; aw += c * v.w;
            }
            float dn = dinv[n];
            float s2 = dn * dn;
            float4 xv = *(const float4*)(xc + ((size_t)n << 7));
            ax += s2 * xv.x; ay += s2 * xv.y; az += s2 * xv.z; aw += s2 * xv.w;
            *(float4*)&ldsA[nl * ALDS + (l << 2)] = make_float4(ax, ay, az, aw);
        }
    }
    __syncthreads();

    int lane = tid & 63, w = tid >> 6;
    int colb = lane & 15, kg = lane >> 4;
    int rowb = kg * 4;

    // ---- stage A (16x128) as split-bf16 A-fragments: thread = (kt=w, lane) ----
    {
        const float* ap = ldsA + colb * ALDS + w * 32 + kg * 8;
        float4 f0 = *(const float4*)ap;
        float4 f1 = *(const float4*)(ap + 4);
        float fs[8] = {f0.x, f0.y, f0.z, f0.w, f1.x, f1.y, f1.z, f1.w};
        FragU h, l;
        #pragma unroll
        for (int j = 0; j < 8; ++j) {
            h.us[j] = f2bf(fs[j]);
            l.us[j] = f2bf(fs[j] - __uint_as_float((unsigned)h.us[j] << 16));
        }
        *(uint4*)&ApkH[tid * 8] = h.q;
        *(uint4*)&ApkL[tid * 8] = l.q;
    }
    __syncthreads();

    // ---- phase 1: C(16x256) = relu(A @ W1 + b1) ----
    {
        f32x4 acc[4];
        #pragma unroll
        for (int f = 0; f < 4; ++f) acc[f] = (f32x4){0.f, 0.f, 0.f, 0.f};
        #pragma unroll
        for (int kt = 0; kt < 4; ++kt) {
            bf16x8 ah = *(const bf16x8*)&ApkH[(kt * 64 + lane) * 8];
            bf16x8 al = *(const bf16x8*)&ApkL[(kt * 64 + lane) * 8];
            #pragma unroll
            for (int f = 0; f < 4; ++f) {
                int nt = w * 4 + f;
                size_t o8 = ((size_t)(kt * 16 + nt) * 64 + lane) * 8;
                bf16x8 bh = *(const bf16x8*)&W1h[o8];
                bf16x8 bl = *(const bf16x8*)&W1l[o8];
                acc[f] = __builtin_amdgcn_mfma_f32_16x16x32_bf16(ah, bh, acc[f], 0, 0, 0);
                acc[f] = __builtin_amdgcn_mfma_f32_16x16x32_bf16(ah, bl, acc[f], 0, 0, 0);
                acc[f] = __builtin_amdgcn_mfma_f32_16x16x32_bf16(al, bh, acc[f], 0, 0, 0);
                acc[f] = __builtin_amdgcn_mfma_f32_16x16x32_bf16(al, bl, acc[f], 0, 0, 0);
            }
        }
        #pragma unroll
        for (int f = 0; f < 4; ++f) {
            int nt = w * 4 + f;
            float bias = b1[nt * 16 + colb];
            #pragma unroll
            for (int r = 0; r < 4; ++r)
                ldsC[(rowb + r) * CLDS + nt * 16 + colb] = fmaxf(acc[f][r] + bias, 0.f);
        }
    }
    __syncthreads();

    // ---- phase 2: G(16x64) = C @ W2 ----
    {
        f32x4 acc2 = (f32x4){0.f, 0.f, 0.f, 0.f};
        #pragma unroll
        for (int kt = 0; kt < 8; ++kt) {
            const float* cp = &ldsC[colb * CLDS + kt * 32 + kg * 8];
            float4 c0 = *(const float4*)cp;
            float4 c1 = *(const float4*)(cp + 4);
            float fs[8] = {c0.x, c0.y, c0.z, c0.w, c1.x, c1.y, c1.z, c1.w};
            FragU h, l;
            #pragma unroll
            for (int j = 0; j < 8; ++j) {
                h.us[j] = f2bf(fs[j]);
                l.us[j] = f2bf(fs[j] - __uint_as_float((unsigned)h.us[j] << 16));
            }
            size_t o8 = ((size_t)(kt * 4 + w) * 64 + lane) * 8;
            bf16x8 bh = *(const bf16x8*)&W2h[o8];
            bf16x8 bl = *(const bf16x8*)&W2l[o8];
            acc2 = __builtin_amdgcn_mfma_f32_16x16x32_bf16(h.v, bh, acc2, 0, 0, 0);
            acc2 = __builtin_amdgcn_mfma_f32_16x16x32_bf16(h.v, bl, acc2, 0, 0, 0);
            acc2 = __builtin_amdgcn_mfma_f32_16x16x32_bf16(l.v, bh, acc2, 0, 0, 0);
            acc2 = __builtin_amdgcn_mfma_f32_16x16x32_bf16(l.v, bl, acc2, 0, 0, 0);
        }
        #pragma unroll
        for (int r = 0; r < 4; ++r)
            G[(size_t)(row0 + rowb + r) * FOUT + w * 16 + colb] = acc2[r];
    }
}

// ---------- layer-2 aggregate + bias + softmax: 16-lane group x float4 per node ----------
__global__ __launch_bounds__(256) void k_agg2sm(
    const float* __restrict__ G, const int2* __restrict__ ep,
    const float* __restrict__ dinv, const int* __restrict__ off,
    const float* __restrict__ b2, float* __restrict__ out) {
    int q = threadIdx.x >> 4, l = threadIdx.x & 15;
    int n = (blockIdx.x << 4) + q;
    const float* gc = G + (l << 2);
    float ax = 0.f, ay = 0.f, az = 0.f, aw = 0.f;
    int p = off[n], p1 = off[n + 1];
    for (; p + 4 <= p1; p += 4) {
        int2 e0 = ep[p], e1 = ep[p + 1], e2 = ep[p + 2], e3 = ep[p + 3];
        float4 v0 = *(const float4*)(gc + ((size_t)e0.x << 6));
        float4 v1 = *(const float4*)(gc + ((size_t)e1.x << 6));
        float4 v2 = *(const float4*)(gc + ((size_t)e2.x << 6));
        float4 v3 = *(const float4*)(gc + ((size_t)e3.x << 6));
        float c0 = __int_as_float(e0.y), c1 = __int_as_float(e1.y);
        float c2 = __int_as_float(e2.y), c3 = __int_as_float(e3.y);
        ax += c0 * v0.x + c1 * v1.x + c2 * v2.x + c3 * v3.x;
        ay += c0 * v0.y + c1 * v1.y + c2 * v2.y + c3 * v3.y;
        az += c0 * v0.z + c1 * v1.z + c2 * v2.z + c3 * v3.z;
        aw += c0 * v0.w + c1 * v1.w + c2 * v2.w + c3 * v3.w;
    }
    for (; p < p1; ++p) {
        int2 e = ep[p];
        float4 v = *(const float4*)(gc + ((size_t)e.x << 6));
        float c = __int_as_float(e.y);
        ax += c * v.x; ay += c * v.y; az += c * v.z; aw += c * v.w;
    }
    float dn = dinv[n];
    float s2 = dn * dn;
    float4 gv = *(const float4*)(gc + ((size_t)n << 6));
    float4 bv = *(const float4*)&b2[l << 2];
    ax += s2 * gv.x + bv.x; ay += s2 * gv.y + bv.y;
    az += s2 * gv.z + bv.z; aw += s2 * gv.w + bv.w;

    float m = fmaxf(fmaxf(ax, ay), fmaxf(az, aw));
    #pragma unroll
    for (int d = 8; d; d >>= 1) m = fmaxf(m, __shfl_xor(m, d, 16));
    float ex = __expf(ax - m), ey = __expf(ay - m), ez = __expf(az - m), ew_ = __expf(aw - m);
    float s = ex + ey + ez + ew_;
    #pragma unroll
    for (int d = 8; d; d >>= 1) s += __shfl_xor(s, d, 16);
    float inv = 1.0f / s;
    *(float4*)&out[((size_t)n << 6) + (l << 2)] =
        make_float4(ex * inv, ey * inv, ez * inv, ew_ * inv);
}

extern "C" void kernel_launch(void* const* d_in, const int* in_sizes, int n_in,
                              void* d_out, int out_size, void* d_ws, size_t ws_size,
                              hipStream_t stream) {
    const float* x  = (const float*)d_in[0];
    const int*   ei = (const int*)d_in[1];     // [2, NE]
    const float* ew = (const float*)d_in[2];
    // d_in[3..6] = W_gat, att_src, att_dst, b_gat — DEAD in the reference.
    const float* W1 = (const float*)d_in[7];
    const float* b1 = (const float*)d_in[8];
    const float* W2 = (const float*)d_in[9];
    const float* b2 = (const float*)d_in[10];

    const int* srcv = ei;
    const int* dstv = ei + NE;

    char* ws = (char*)d_ws;
    size_t o = 0;
    auto alloc = [&](size_t bytes) {
        void* p = ws + o;
        o = (o + bytes + 255) & ~(size_t)255;
        return p;
    };
    unsigned long long* P = (unsigned long long*)alloc(NN * sizeof(unsigned long long));
    float* dinv = (float*)alloc(NN * sizeof(float));
    int*   cnt  = (int*)alloc(NN * sizeof(int));
    int*   off  = (int*)alloc((NN + 1) * sizeof(int));
    int*   bsum = (int*)alloc(32 * sizeof(int));
    int2*  ep   = (int2*)alloc((size_t)NE * sizeof(int2));
    float* G    = (float*)alloc((size_t)NN * FOUT * sizeof(float));
    unsigned short* W1h = (unsigned short*)alloc(FIN * FHID * sizeof(unsigned short));
    unsigned short* W1l = (unsigned short*)alloc(FIN * FHID * sizeof(unsigned short));
    unsigned short* W2h = (unsigned short*)alloc(FHID * FOUT * sizeof(unsigned short));
    unsigned short* W2l = (unsigned short*)alloc(FHID * FOUT * sizeof(unsigned short));

    k_prep   <<<103, 256, 0, stream>>>(P, W1, W1h, W1l, W2, W2h, W2l);
    k_deg    <<<(NE + 255) / 256, 256, 0, stream>>>(dstv, ew, P);
    k_scan1  <<<20, 1024, 0, stream>>>(P, dinv, off, bsum);
    k_scan3  <<<20, 1024, 0, stream>>>(off, bsum, cnt);
    k_scatter<<<(NE + 255) / 256, 256, 0, stream>>>(srcv, dstv, ew, dinv, off, cnt, ep);
    k_aggmlp <<<NN / 16, 256, 0, stream>>>(x, ep, dinv, off, W1h, W1l, b1, W2h, W2l, G);
    k_agg2sm <<<NN / 16, 256, 0, stream>>>(G, ep, dinv, off, b2, (float*)d_out);
}

// Round 9
// 93.305 us; speedup vs baseline: 1.3371x; 1.0607x over previous
//
#include <hip/hip_runtime.h>
#include <math.h>

#define NN   20000
#define NE   320000
#define FIN  128
#define FHID 256
#define FOUT 64
#define CLDS 268   // fp32 C-tile LDS row stride
#define ALDS 132   // fp32 A-tile LDS row stride (132%32=4 -> 2-way max on frag reads)

typedef __attribute__((ext_vector_type(8))) __bf16 bf16x8;
typedef __attribute__((ext_vector_type(4))) float  f32x4;

union FragU { unsigned short us[8]; bf16x8 v; uint4 q; };

static __device__ __forceinline__ unsigned short f2bf(float f) {
    unsigned u = __float_as_uint(f);
    return (unsigned short)((u + 0x7FFFu + ((u >> 16) & 1u)) >> 16);
}

// ---------- W-pack device body: W [K][N] fp32 -> MFMA B-fragment tiles, hi/lo bf16 ----------
static __device__ __forceinline__ void wpack_body(
    const float* __restrict__ W, int K, int N,
    unsigned short* __restrict__ hi, unsigned short* __restrict__ lo, int t) {
    int NT = N >> 4, KT = K >> 5;
    if (t >= KT * NT * 64) return;
    int lane = t & 63;
    int tile = t >> 6;
    int nt = tile % NT, kt = tile / NT;
    int col = nt * 16 + (lane & 15);
    int k0 = kt * 32 + (lane >> 4) * 8;
    #pragma unroll
    for (int j = 0; j < 8; ++j) {
        float w = W[(size_t)(k0 + j) * N + col];
        unsigned short h = f2bf(w);
        unsigned short l = f2bf(w - __uint_as_float((unsigned)h << 16));
        hi[(size_t)t * 8 + j] = h;
        lo[(size_t)t * 8 + j] = l;
    }
}

// ---------- prep: init packed deg/cnt + pack W1 + pack W2 (blockIdx-partitioned) ----------
// P[i] layout: bits[63:40] = edge count, bits[39:0] = deg * 2^32 (fixed point).
__global__ void k_prep(unsigned long long* __restrict__ P,
                       const float* __restrict__ W1, unsigned short* __restrict__ W1h,
                       unsigned short* __restrict__ W1l,
                       const float* __restrict__ W2, unsigned short* __restrict__ W2h,
                       unsigned short* __restrict__ W2l) {
    int b = blockIdx.x, tid = threadIdx.x;
    if (b < 79) {
        int i = b * 256 + tid;
        if (i < NN) P[i] = (1ULL << 32);
    } else if (b < 95) {
        wpack_body(W1, FIN, FHID, W1h, W1l, (b - 79) * 256 + tid);
    } else {
        wpack_body(W2, FHID, FOUT, W2h, W2l, (b - 95) * 256 + tid);
    }
}

// ---------- degree + count in ONE u64 atomic per edge ----------
__global__ void k_deg(const int* __restrict__ dst, const float* __restrict__ ew,
                      unsigned long long* __restrict__ P) {
    int e = blockIdx.x * blockDim.x + threadIdx.x;
    if (e < NE) {
        int d = dst[e];
        unsigned long long add = (1ULL << 40) + (unsigned long long)(ew[e] * 4294967296.0f);
        atomicAdd(&P[d], add);
    }
}

// scan stage 1: per-block inclusive scan of counts; also dinv from packed deg
__global__ __launch_bounds__(1024) void k_scan1(
    const unsigned long long* __restrict__ P,
    float* __restrict__ dinv, int* __restrict__ off, int* __restrict__ bsum) {
    __shared__ int wsum[16];
    int tid = threadIdx.x, lane = tid & 63, w = tid >> 6;
    int i = blockIdx.x * 1024 + tid;
    unsigned long long pv = (i < NN) ? P[i] : 0ULL;
    int v = (int)(pv >> 40);
    if (i < NN) {
        float dg = (float)(pv & 0xFFFFFFFFFFULL) * 0x1p-32f;
        dinv[i] = dg > 0.0f ? rsqrtf(dg) : 0.0f;
    }
    int sc = v;
    #pragma unroll
    for (int d = 1; d < 64; d <<= 1) {
        int t = __shfl_up(sc, d, 64);
        if (lane >= d) sc += t;
    }
    if (lane == 63) wsum[w] = sc;
    __syncthreads();
    if (w == 0) {
        int ws_ = (lane < 16) ? wsum[lane] : 0;
        #pragma unroll
        for (int d = 1; d < 16; d <<= 1) {
            int t = __shfl_up(ws_, d, 64);
            if (lane >= d) ws_ += t;
        }
        if (lane < 16) wsum[lane] = ws_;
    }
    __syncthreads();
    int inc = sc + (w ? wsum[w - 1] : 0);
    if (i < NN) off[i + 1] = inc;
    if (tid == 1023) bsum[blockIdx.x] = inc;
}

// scan stage 2+3 fused: each block inlines the 20-element block-sum scan, adds prefix, zeroes cnt
__global__ __launch_bounds__(1024) void k_scan3(int* __restrict__ off,
                                                const int* __restrict__ bsum,
                                                int* __restrict__ cnt) {
    __shared__ int sp;
    int tid = threadIdx.x;
    if (tid < 32) {
        int v = (tid < 20) ? bsum[tid] : 0;
        int sc = v;
        #pragma unroll
        for (int d = 1; d < 32; d <<= 1) {
            int t = __shfl_up(sc, d, 32);
            if (tid >= d) sc += t;
        }
        if (tid == (int)blockIdx.x) sp = sc - v;   // exclusive prefix for this block
    }
    __syncthreads();
    int i = blockIdx.x * 1024 + tid;
    if (i < NN) { off[i + 1] += sp; cnt[i] = 0; }
    if (i == 0) off[0] = 0;
}

// scatter with fully-precomputed coefficient: coef = ew * dinv[s] * dinv[d]
__global__ void k_scatter(const int* __restrict__ src, const int* __restrict__ dst,
                          const float* __restrict__ ew, const float* __restrict__ dinv,
                          const int* __restrict__ off, int* __restrict__ cnt,
                          int2* __restrict__ ep) {
    int e = blockIdx.x * blockDim.x + threadIdx.x;
    if (e < NE) {
        int d = dst[e], s = src[e];
        float c = ew[e] * dinv[s] * dinv[d];
        int p = off[d] + atomicAdd(&cnt[d], 1);
        ep[p] = make_int2(s, __float_as_int(c));
    }
}

// ---------- FUSED: A-rows aggregate (16 nodes) -> split-bf16 MFMA MLP -> G ----------
// LDS regions are OVERLAPPED (temporally disjoint): total 17.2 KB -> 8 blocks/CU.
//   [0, 8448)        ldsA   (phase 0 output, dead after frag staging)
//   [8448, 12544)    ApkH   (dead after phase-1 MFMAs)
//   [12544, 16640)   ApkL
//   [0, 17152)       ldsC   (written AFTER a barrier post-MFMA, read in phase 2)
__global__ __launch_bounds__(256, 8) void k_aggmlp(
    const float* __restrict__ x, const int2* __restrict__ ep,
    const float* __restrict__ dinv, const int* __restrict__ off,
    const unsigned short* __restrict__ W1h, const unsigned short* __restrict__ W1l,
    const float* __restrict__ b1,
    const unsigned short* __restrict__ W2h, const unsigned short* __restrict__ W2l,
    float* __restrict__ G) {
    __shared__ char smem[16 * CLDS * 4];          // 17152 B
    float* ldsA = (float*)smem;
    unsigned short* ApkH = (unsigned short*)(smem + 8448);
    unsigned short* ApkL = (unsigned short*)(smem + 12544);
    float* ldsC = (float*)smem;
    int tid = threadIdx.x;
    int row0 = blockIdx.x * 16;

    // ---- phase 0: aggregate 16 node rows into ldsA ----
    {
        int hw = tid >> 5, l = tid & 31;
        const float* xc = x + (l << 2);
        #pragma unroll
        for (int rep = 0; rep < 2; ++rep) {
            int nl = hw + rep * 8;
            int n = row0 + nl;
            float ax = 0.f, ay = 0.f, az = 0.f, aw = 0.f;
            int p = off[n], p1 = off[n + 1];
            for (; p + 4 <= p1; p += 4) {
                int2 e0 = ep[p], e1 = ep[p + 1], e2 = ep[p + 2], e3 = ep[p + 3];
                float4 v0 = *(const float4*)(xc + ((size_t)e0.x << 7));
                float4 v1 = *(const float4*)(xc + ((size_t)e1.x << 7));
                float4 v2 = *(const float4*)(xc + ((size_t)e2.x << 7));
                float4 v3 = *(const float4*)(xc + ((size_t)e3.x << 7));
                float c0 = __int_as_float(e0.y), c1 = __int_as_float(e1.y);
                float c2 = __int_as_float(e2.y), c3 = __int_as_float(e3.y);
                ax += c0 * v0.x + c1 * v1.x + c2 * v2.x + c3 * v3.x;
                ay += c0 * v0.y + c1 * v1.y + c2 * v2.y + c3 * v3.y;
                az += c0 * v0.z + c1 * v1.z + c2 * v2.z + c3 * v3.z;
                aw += c0 * v0.w + c1 * v1.w + c2 * v2.w + c3 * v3.w;
            }
            for (; p < p1; ++p) {
                int2 e = ep[p];
                float4 v = *(const float4*)(xc + ((size_t)e.x << 7));
                float c = __int_as_float(e.y);
                ax += c * v.x; ay += c * v.y; az += c * v.z; aw += c * v.w;
            }
            float dn = dinv[n];
            float s2 = dn * dn;
            float4 xv = *(const float4*)(xc + ((size_t)n << 7));
            ax += s2 * xv.x; ay += s2 * xv.y; az += s2 * xv.z; aw += s2 * xv.w;
            *(float4*)&ldsA[nl * ALDS + (l << 2)] = make_float4(ax, ay, az, aw);
        }
    }
    __syncthreads();

    int lane = tid & 63, w = tid >> 6;
    int colb = lane & 15, kg = lane >> 4;
    int rowb = kg * 4;

    // ---- stage A (16x128) as split-bf16 A-fragments (reads ldsA, writes Apk) ----
    {
        const float* ap = ldsA + colb * ALDS + w * 32 + kg * 8;
        float4 f0 = *(const float4*)ap;
        float4 f1 = *(const float4*)(ap + 4);
        float fs[8] = {f0.x, f0.y, f0.z, f0.w, f1.x, f1.y, f1.z, f1.w};
        FragU h, l;
        #pragma unroll
        for (int j = 0; j < 8; ++j) {
            h.us[j] = f2bf(fs[j]);
            l.us[j] = f2bf(fs[j] - __uint_as_float((unsigned)h.us[j] << 16));
        }
        *(uint4*)&ApkH[tid * 8] = h.q;
        *(uint4*)&ApkL[tid * 8] = l.q;
    }
    __syncthreads();

    // ---- phase 1: C(16x256) = relu(A @ W1 + b1) ----
    {
        f32x4 acc[4];
        #pragma unroll
        for (int f = 0; f < 4; ++f) acc[f] = (f32x4){0.f, 0.f, 0.f, 0.f};
        #pragma unroll
        for (int kt = 0; kt < 4; ++kt) {
            bf16x8 ah = *(const bf16x8*)&ApkH[(kt * 64 + lane) * 8];
            bf16x8 al = *(const bf16x8*)&ApkL[(kt * 64 + lane) * 8];
            #pragma unroll
            for (int f = 0; f < 4; ++f) {
                int nt = w * 4 + f;
                size_t o8 = ((size_t)(kt * 16 + nt) * 64 + lane) * 8;
                bf16x8 bh = *(const bf16x8*)&W1h[o8];
                bf16x8 bl = *(const bf16x8*)&W1l[o8];
                acc[f] = __builtin_amdgcn_mfma_f32_16x16x32_bf16(ah, bh, acc[f], 0, 0, 0);
                acc[f] = __builtin_amdgcn_mfma_f32_16x16x32_bf16(ah, bl, acc[f], 0, 0, 0);
                acc[f] = __builtin_amdgcn_mfma_f32_16x16x32_bf16(al, bh, acc[f], 0, 0, 0);
                acc[f] = __builtin_amdgcn_mfma_f32_16x16x32_bf16(al, bl, acc[f], 0, 0, 0);
            }
        }
        // all Apk reads complete chip-wide before ldsC (overlapping memory) is written
        __syncthreads();
        #pragma unroll
        for (int f = 0; f < 4; ++f) {
            int nt = w * 4 + f;
            float bias = b1[nt * 16 + colb];
            #pragma unroll
            for (int r = 0; r < 4; ++r)
                ldsC[(rowb + r) * CLDS + nt * 16 + colb] = fmaxf(acc[f][r] + bias, 0.f);
        }
    }
    __syncthreads();

    // ---- phase 2: G(16x64) = C @ W2 ----
    {
        f32x4 acc2 = (f32x4){0.f, 0.f, 0.f, 0.f};
        #pragma unroll
        for (int kt = 0; kt < 8; ++kt) {
            const float* cp = &ldsC[colb * CLDS + kt * 32 + kg * 8];
            float4 c0 = *(const float4*)cp;
            float4 c1 = *(const float4*)(cp + 4);
            float fs[8] = {c0.x, c0.y, c0.z, c0.w, c1.x, c1.y, c1.z, c1.w};
            FragU h, l;
            #pragma unroll
            for (int j = 0; j < 8; ++j) {
                h.us[j] = f2bf(fs[j]);
                l.us[j] = f2bf(fs[j] - __uint_as_float((unsigned)h.us[j] << 16));
            }
            size_t o8 = ((size_t)(kt * 4 + w) * 64 + lane) * 8;
            bf16x8 bh = *(const bf16x8*)&W2h[o8];
            bf16x8 bl = *(const bf16x8*)&W2l[o8];
            acc2 = __builtin_amdgcn_mfma_f32_16x16x32_bf16(h.v, bh, acc2, 0, 0, 0);
            acc2 = __builtin_amdgcn_mfma_f32_16x16x32_bf16(h.v, bl, acc2, 0, 0, 0);
            acc2 = __builtin_amdgcn_mfma_f32_16x16x32_bf16(l.v, bh, acc2, 0, 0, 0);
            acc2 = __builtin_amdgcn_mfma_f32_16x16x32_bf16(l.v, bl, acc2, 0, 0, 0);
        }
        #pragma unroll
        for (int r = 0; r < 4; ++r)
            G[(size_t)(row0 + rowb + r) * FOUT + w * 16 + colb] = acc2[r];
    }
}

// ---------- layer-2 aggregate + bias + softmax: 16-lane group x float4 per node ----------
__global__ __launch_bounds__(256) void k_agg2sm(
    const float* __restrict__ G, const int2* __restrict__ ep,
    const float* __restrict__ dinv, const int* __restrict__ off,
    const float* __restrict__ b2, float* __restrict__ out) {
    int q = threadIdx.x >> 4, l = threadIdx.x & 15;
    int n = (blockIdx.x << 4) + q;
    const float* gc = G + (l << 2);
    float ax = 0.f, ay = 0.f, az = 0.f, aw = 0.f;
    int p = off[n], p1 = off[n + 1];
    for (; p + 4 <= p1; p += 4) {
        int2 e0 = ep[p], e1 = ep[p + 1], e2 = ep[p + 2], e3 = ep[p + 3];
        float4 v0 = *(const float4*)(gc + ((size_t)e0.x << 6));
        float4 v1 = *(const float4*)(gc + ((size_t)e1.x << 6));
        float4 v2 = *(const float4*)(gc + ((size_t)e2.x << 6));
        float4 v3 = *(const float4*)(gc + ((size_t)e3.x << 6));
        float c0 = __int_as_float(e0.y), c1 = __int_as_float(e1.y);
        float c2 = __int_as_float(e2.y), c3 = __int_as_float(e3.y);
        ax += c0 * v0.x + c1 * v1.x + c2 * v2.x + c3 * v3.x;
        ay += c0 * v0.y + c1 * v1.y + c2 * v2.y + c3 * v3.y;
        az += c0 * v0.z + c1 * v1.z + c2 * v2.z + c3 * v3.z;
        aw += c0 * v0.w + c1 * v1.w + c2 * v2.w + c3 * v3.w;
    }
    for (; p < p1; ++p) {
        int2 e = ep[p];
        float4 v = *(const float4*)(gc + ((size_t)e.x << 6));
        float c = __int_as_float(e.y);
        ax += c * v.x; ay += c * v.y; az += c * v.z; aw += c * v.w;
    }
    float dn = dinv[n];
    float s2 = dn * dn;
    float4 gv = *(const float4*)(gc + ((size_t)n << 6));
    float4 bv = *(const float4*)&b2[l << 2];
    ax += s2 * gv.x + bv.x; ay += s2 * gv.y + bv.y;
    az += s2 * gv.z + bv.z; aw += s2 * gv.w + bv.w;

    float m = fmaxf(fmaxf(ax, ay), fmaxf(az, aw));
    #pragma unroll
    for (int d = 8; d; d >>= 1) m = fmaxf(m, __shfl_xor(m, d, 16));
    float ex = __expf(ax - m), ey = __expf(ay - m), ez = __expf(az - m), ew_ = __expf(aw - m);
    float s = ex + ey + ez + ew_;
    #pragma unroll
    for (int d = 8; d; d >>= 1) s += __shfl_xor(s, d, 16);
    float inv = 1.0f / s;
    *(float4*)&out[((size_t)n << 6) + (l << 2)] =
        make_float4(ex * inv, ey * inv, ez * inv, ew_ * inv);
}

extern "C" void kernel_launch(void* const* d_in, const int* in_sizes, int n_in,
                              void* d_out, int out_size, void* d_ws, size_t ws_size,
                              hipStream_t stream) {
    const float* x  = (const float*)d_in[0];
    const int*   ei = (const int*)d_in[1];     // [2, NE]
    const float* ew = (const float*)d_in[2];
    // d_in[3..6] = W_gat, att_src, att_dst, b_gat — DEAD in the reference.
    const float* W1 = (const float*)d_in[7];
    const float* b1 = (const float*)d_in[8];
    const float* W2 = (const float*)d_in[9];
    const float* b2 = (const float*)d_in[10];

    const int* srcv = ei;
    const int* dstv = ei + NE;

    char* ws = (char*)d_ws;
    size_t o = 0;
    auto alloc = [&](size_t bytes) {
        void* p = ws + o;
        o = (o + bytes + 255) & ~(size_t)255;
        return p;
    };
    unsigned long long* P = (unsigned long long*)alloc(NN * sizeof(unsigned long long));
    float* dinv = (float*)alloc(NN * sizeof(float));
    int*   cnt  = (int*)alloc(NN * sizeof(int));
    int*   off  = (int*)alloc((NN + 1) * sizeof(int));
    int*   bsum = (int*)alloc(32 * sizeof(int));
    int2*  ep   = (int2*)alloc((size_t)NE * sizeof(int2));
    float* G    = (float*)alloc((size_t)NN * FOUT * sizeof(float));
    unsigned short* W1h = (unsigned short*)alloc(FIN * FHID * sizeof(unsigned short));
    unsigned short* W1l = (unsigned short*)alloc(FIN * FHID * sizeof(unsigned short));
    unsigned short* W2h = (unsigned short*)alloc(FHID * FOUT * sizeof(unsigned short));
    unsigned short* W2l = (unsigned short*)alloc(FHID * FOUT * sizeof(unsigned short));

    k_prep   <<<103, 256, 0, stream>>>(P, W1, W1h, W1l, W2, W2h, W2l);
    k_deg    <<<(NE + 255) / 256, 256, 0, stream>>>(dstv, ew, P);
    k_scan1  <<<20, 1024, 0, stream>>>(P, dinv, off, bsum);
    k_scan3  <<<20, 1024, 0, stream>>>(off, bsum, cnt);
    k_scatter<<<(NE + 255) / 256, 256, 0, stream>>>(srcv, dstv, ew, dinv, off, cnt, ep);
    k_aggmlp <<<NN / 16, 256, 0, stream>>>(x, ep, dinv, off, W1h, W1l, b1, W2h, W2l, G);
    k_agg2sm <<<NN / 16, 256, 0, stream>>>(G, ep, dinv, off, b2, (float*)d_out);
}